// Round 7
// baseline (1481.218 us; speedup 1.0000x reference)
//
#include <hip/hip_runtime.h>

typedef _Float16 f16;
typedef _Float16 f16x8 __attribute__((ext_vector_type(8)));
typedef float    f32x4 __attribute__((ext_vector_type(4)));
typedef float    f32x2 __attribute__((ext_vector_type(2)));

#define NB   16
#define NP   8192
#define NG   512
#define NM   32
#define ENC  384
#define NROWS (NB * NG * NM)      // 262144 total rows

// ---------------------------------------------------------------------------
// helpers
// ---------------------------------------------------------------------------
__device__ __forceinline__ void gl_lds16(const void* g, void* l) {
  __builtin_amdgcn_global_load_lds((const __attribute__((address_space(1))) unsigned int*)g,
                                   (__attribute__((address_space(3))) unsigned int*)l, 16, 0, 0);
}

__device__ __forceinline__ f32x2 pk_add(f32x2 a, f32x2 b) {
  f32x2 d;
  asm("v_pk_add_f32 %0, %1, %2" : "=v"(d) : "v"(a), "v"(b));
  return d;
}
__device__ __forceinline__ f32x2 pk_mul(f32x2 a, f32x2 b) {
  f32x2 d;
  asm("v_pk_mul_f32 %0, %1, %2" : "=v"(d) : "v"(a), "v"(b));
  return d;
}

__device__ __forceinline__ unsigned long long kmax(unsigned long long a, unsigned long long b) {
  return a > b ? a : b;
}
__device__ __forceinline__ unsigned long long kmin(unsigned long long a, unsigned long long b) {
  return a < b ? a : b;
}

template <int CTRL>
__device__ __forceinline__ unsigned long long dpp_kmax(unsigned long long k) {
  int lo = (int)(unsigned)(k & 0xFFFFFFFFull);
  int hi = (int)(unsigned)(k >> 32);
  int olo = __builtin_amdgcn_update_dpp(lo, lo, CTRL, 0xF, 0xF, false);
  int ohi = __builtin_amdgcn_update_dpp(hi, hi, CTRL, 0xF, 0xF, false);
  unsigned long long o = ((unsigned long long)(unsigned)ohi << 32) | (unsigned)olo;
  return kmax(k, o);
}
template <int CTRL>
__device__ __forceinline__ unsigned long long dpp_kmin(unsigned long long k) {
  int lo = (int)(unsigned)(k & 0xFFFFFFFFull);
  int hi = (int)(unsigned)(k >> 32);
  int olo = __builtin_amdgcn_update_dpp(lo, lo, CTRL, 0xF, 0xF, false);
  int ohi = __builtin_amdgcn_update_dpp(hi, hi, CTRL, 0xF, 0xF, false);
  unsigned long long o = ((unsigned long long)(unsigned)ohi << 32) | (unsigned)olo;
  return kmin(k, o);
}
__device__ __forceinline__ unsigned long long swz16_kmax(unsigned long long k) {
  int lo = (int)(unsigned)(k & 0xFFFFFFFFull);
  int hi = (int)(unsigned)(k >> 32);
  int olo = __builtin_amdgcn_ds_swizzle(lo, 0x401F);
  int ohi = __builtin_amdgcn_ds_swizzle(hi, 0x401F);
  unsigned long long o = ((unsigned long long)(unsigned)ohi << 32) | (unsigned)olo;
  return kmax(k, o);
}
__device__ __forceinline__ unsigned long long swz16_kmin(unsigned long long k) {
  int lo = (int)(unsigned)(k & 0xFFFFFFFFull);
  int hi = (int)(unsigned)(k >> 32);
  int olo = __builtin_amdgcn_ds_swizzle(lo, 0x401F);
  int ohi = __builtin_amdgcn_ds_swizzle(hi, 0x401F);
  unsigned long long o = ((unsigned long long)(unsigned)ohi << 32) | (unsigned)olo;
  return kmin(k, o);
}

#define DPP_QUAD_XOR1 0xB1
#define DPP_QUAD_XOR2 0x4E
#define DPP_HALF_MIRR 0x141
#define DPP_ROW_MIRR  0x140

// ---------------------------------------------------------------------------
// FPS v4 (reverted, known-good 480us)
// ---------------------------------------------------------------------------
__global__ __launch_bounds__(512) void fps_kernel(const float* __restrict__ pts,
                                                  float* __restrict__ centers) {
#pragma clang fp contract(off)
  const int b = blockIdx.x;
  const float* pb = pts + (size_t)b * NP * 3;
  const int t = threadIdx.x;
  const int lane = t & 63, wid = t >> 6;
  __shared__ float spx[NP], spy[NP], spz[NP];
  __shared__ unsigned long long swk[2][16];
  f32x2 px2[8], py2[8], pz2[8];
  float dd[16];
#pragma unroll
  for (int i = 0; i < 16; ++i) {
    int idx = t + i * 512;
    float x = pb[idx * 3 + 0], y = pb[idx * 3 + 1], z = pb[idx * 3 + 2];
    px2[i >> 1][i & 1] = x; py2[i >> 1][i & 1] = y; pz2[i >> 1][i & 1] = z;
    dd[i] = 1e10f;
    spx[idx] = x; spy[idx] = y; spz[idx] = z;
  }
  __syncthreads();
  float cx = spx[0], cy = spy[0], cz = spz[0];
  for (int g = 0; g < NG; ++g) {
    if (t == 0) {
      float* c = centers + ((size_t)b * NG + g) * 3;
      c[0] = cx; c[1] = cy; c[2] = cz;
    }
    f32x2 ncx = {-cx, -cx}, ncy = {-cy, -cy}, ncz = {-cz, -cz};
    float best = -1.0f; int bslot = 0;
#pragma unroll
    for (int p = 0; p < 8; ++p) {
      f32x2 dx = pk_add(px2[p], ncx);
      f32x2 dy = pk_add(py2[p], ncy);
      f32x2 dz = pk_add(pz2[p], ncz);
      f32x2 d2 = pk_add(pk_add(pk_mul(dx, dx), pk_mul(dy, dy)), pk_mul(dz, dz));
      dd[2 * p] = fminf(dd[2 * p], d2[0]);
      if (dd[2 * p] > best) { best = dd[2 * p]; bslot = 2 * p; }
      dd[2 * p + 1] = fminf(dd[2 * p + 1], d2[1]);
      if (dd[2 * p + 1] > best) { best = dd[2 * p + 1]; bslot = 2 * p + 1; }
    }
    int bidx = t + bslot * 512;
    unsigned long long key =
        ((unsigned long long)__float_as_uint(best) << 13) | (unsigned)(8191 - bidx);
    key = dpp_kmax<DPP_QUAD_XOR1>(key);
    key = dpp_kmax<DPP_QUAD_XOR2>(key);
    key = dpp_kmax<DPP_HALF_MIRR>(key);
    key = dpp_kmax<DPP_ROW_MIRR>(key);
    key = swz16_kmax(key);
    const int p = g & 1;
    if ((lane & 31) == 0) swk[p][wid * 2 + (lane >> 5)] = key;
    __syncthreads();
    unsigned long long k2 = swk[p][lane & 15];
    k2 = dpp_kmax<DPP_QUAD_XOR1>(k2);
    k2 = dpp_kmax<DPP_QUAD_XOR2>(k2);
    k2 = dpp_kmax<DPP_HALF_MIRR>(k2);
    k2 = dpp_kmax<DPP_ROW_MIRR>(k2);
    int widx = 8191 - (int)(k2 & 0x1FFFull);
    cx = spx[widx]; cy = spy[widx]; cz = spz[widx];
  }
}

// ---------------------------------------------------------------------------
// kNN v3 (unchanged)
// ---------------------------------------------------------------------------
__global__ __launch_bounds__(256) void knn_kernel(const float* __restrict__ pts,
                                                  const float* __restrict__ centers,
                                                  int* __restrict__ knn_idx) {
#pragma clang fp contract(off)
  const int gg = blockIdx.x;
  const int b = gg >> 9;
  const float* pb = pts + (size_t)b * NP * 3;
  const float* c = centers + (size_t)gg * 3;
  const float cx = c[0], cy = c[1], cz = c[2];
  __shared__ unsigned long long swk[2][8];
  const int t = threadIdx.x, lane = t & 63, wid = t >> 6;
  float d[32];
  float lmin = 3e38f; int lidx = 0;
#pragma unroll
  for (int i = 0; i < 32; ++i) {
    int idx = i * 256 + t;
    float dx = __fsub_rn(cx, pb[idx * 3 + 0]);
    float dy = __fsub_rn(cy, pb[idx * 3 + 1]);
    float dz = __fsub_rn(cz, pb[idx * 3 + 2]);
    d[i] = __fadd_rn(__fadd_rn(__fmul_rn(dx, dx), __fmul_rn(dy, dy)), __fmul_rn(dz, dz));
    if (d[i] < lmin) { lmin = d[i]; lidx = idx; }
  }
  int* outp = knn_idx + (size_t)gg * NM;
  for (int r = 0; r < NM; ++r) {
    unsigned long long key =
        ((unsigned long long)__float_as_uint(lmin) << 13) | (unsigned)lidx;
    key = dpp_kmin<DPP_QUAD_XOR1>(key);
    key = dpp_kmin<DPP_QUAD_XOR2>(key);
    key = dpp_kmin<DPP_HALF_MIRR>(key);
    key = dpp_kmin<DPP_ROW_MIRR>(key);
    key = swz16_kmin(key);
    const int p = r & 1;
    if ((lane & 31) == 0) swk[p][wid * 2 + (lane >> 5)] = key;
    __syncthreads();
    unsigned long long k2 = swk[p][lane & 7];
    k2 = dpp_kmin<DPP_QUAD_XOR1>(k2);
    k2 = dpp_kmin<DPP_QUAD_XOR2>(k2);
    k2 = dpp_kmin<DPP_HALF_MIRR>(k2);
    int i0 = (int)(k2 & 0x1FFFull);
    if (t == 0) outp[r] = i0;
    if ((i0 & 255) == t) {
      int slot = i0 >> 8;
      lmin = 3e38f; lidx = 0;
#pragma unroll
      for (int i = 0; i < 32; ++i) {
        float di = (i == slot) ? 3e38f : d[i];
        d[i] = di;
        if (di < lmin) { lmin = di; lidx = i * 256 + t; }
      }
    }
  }
}

// ---------------------------------------------------------------------------
// quant (unchanged)
// ---------------------------------------------------------------------------
__global__ void quant_kernel(const float* __restrict__ W2, const float* __restrict__ W3,
                             const float* __restrict__ W4, const float* __restrict__ Wp2,
                             const float* __restrict__ b1, const float* __restrict__ g1,
                             const float* __restrict__ be1, const float* __restrict__ m1,
                             const float* __restrict__ v1, const float* __restrict__ g2,
                             const float* __restrict__ be2, const float* __restrict__ m2,
                             const float* __restrict__ v2,
                             f16* __restrict__ W2T, f16* __restrict__ W3aT,
                             f16* __restrict__ W3bT, f16* __restrict__ W4T,
                             f16* __restrict__ Wp2T,
                             float* __restrict__ s1, float* __restrict__ sh1,
                             float* __restrict__ s2, float* __restrict__ sh2) {
  int i = blockIdx.x * 256 + threadIdx.x;
  if (i < 32768) { int n = i >> 7, k = i & 127; W2T[i] = (f16)W2[(size_t)k * 256 + n]; return; }
  i -= 32768;
  if (i < 131072) { int n = i >> 8, k = i & 255; W3aT[i] = (f16)W3[(size_t)k * 512 + n]; return; }
  i -= 131072;
  if (i < 131072) { int n = i >> 8, k = i & 255; W3bT[i] = (f16)W3[(size_t)(256 + k) * 512 + n]; return; }
  i -= 131072;
  if (i < 196608) { int n = i >> 9, k = i & 511; W4T[i] = (f16)W4[(size_t)k * 384 + n]; return; }
  i -= 196608;
  if (i < 49152) { int n = i >> 7, k = i & 127; Wp2T[i] = (f16)Wp2[(size_t)k * 384 + n]; return; }
  i -= 49152;
  if (i < 128) {
    float s = g1[i] * rsqrtf(v1[i] + 1e-5f);
    s1[i] = s; sh1[i] = (b1[i] - m1[i]) * s + be1[i];
    return;
  }
  i -= 128;
  if (i < 512) {
    float s = g2[i] * rsqrtf(v2[i] + 1e-5f);
    s2[i] = s; sh2[i] = be2[i] - m2[i] * s;
    return;
  }
}

// ---------------------------------------------------------------------------
// l2f (unchanged): fused gather + L1 MLP + L2 GEMM + fg epilogue (+ f2 write)
// ---------------------------------------------------------------------------
template <int WRITE_F2>
__global__ __launch_bounds__(256) void l2f_kernel(const float* __restrict__ pts,
                                                  const float* __restrict__ centers,
                                                  const int* __restrict__ knn_idx,
                                                  const float* __restrict__ W1,
                                                  const float* __restrict__ s1,
                                                  const float* __restrict__ sh1,
                                                  const f16* __restrict__ W2T,
                                                  const float* __restrict__ b2,
                                                  f16* __restrict__ fg,
                                                  f16* __restrict__ f2, int grow0) {
  __shared__ __align__(16) f16 sF1[128 * 128];
  __shared__ float snb[128][3];
  const int t = threadIdx.x, lane = t & 63, wid = t >> 6;
  const int wr = wid >> 1, wc = wid & 1;
  const int l15 = lane & 15, lhi = lane >> 4;
  const int grow = grow0 + blockIdx.x * 128;
  const int y = blockIdx.y;

  if (t < 128) {
    int row = grow + t;
    int gg = row >> 5;
    int b = gg >> 9;
    int idx = knn_idx[(size_t)gg * NM + (row & 31)];
    const float* p = pts + ((size_t)b * NP + idx) * 3;
    const float* c = centers + (size_t)gg * 3;
    snb[t][0] = p[0] - c[0];
    snb[t][1] = p[1] - c[1];
    snb[t][2] = p[2] - c[2];
  }
  __syncthreads();
  {
    int row = t >> 1, c0 = (t & 1) * 64;
    float nx = snb[row][0], ny = snb[row][1], nz = snb[row][2];
    int sw = (row & 7) << 4;
#pragma unroll
    for (int cc = 0; cc < 64; cc += 8) {
      f16x8 v;
#pragma unroll
      for (int j = 0; j < 8; ++j) {
        int c = c0 + cc + j;
        float a = nx * W1[c] + ny * W1[128 + c] + nz * W1[256 + c];
        a = a * s1[c] + sh1[c];
        v[j] = (f16)fmaxf(a, 0.0f);
      }
      *(f16x8*)((char*)sF1 + row * 256 + (((c0 + cc) * 2) ^ sw)) = v;
    }
  }
  __syncthreads();

  f32x4 acc[4][4];
#pragma unroll
  for (int m = 0; m < 4; ++m)
#pragma unroll
    for (int n = 0; n < 4; ++n) acc[m][n] = (f32x4){0.f, 0.f, 0.f, 0.f};

  const f16* Wb = W2T + (size_t)(y * 128) * 128;
#pragma unroll
  for (int ks = 0; ks < 4; ++ks) {
    f16x8 af[4], bf[4];
#pragma unroll
    for (int m = 0; m < 4; ++m) {
      int row = wr * 64 + m * 16 + l15;
      af[m] = *(const f16x8*)((const char*)sF1 + row * 256 + ((ks * 64 + lhi * 16) ^ ((row & 7) << 4)));
    }
#pragma unroll
    for (int n = 0; n < 4; ++n) {
      int nr = wc * 64 + n * 16 + l15;
      bf[n] = *(const f16x8*)(Wb + (size_t)nr * 128 + ks * 32 + lhi * 8);
    }
#pragma unroll
    for (int m = 0; m < 4; ++m)
#pragma unroll
      for (int n = 0; n < 4; ++n)
        acc[m][n] = __builtin_amdgcn_mfma_f32_16x16x32_f16(af[m], bf[n], acc[m][n], 0, 0, 0);
  }

  float bias[4];
#pragma unroll
  for (int n = 0; n < 4; ++n) bias[n] = b2[y * 128 + wc * 64 + n * 16 + l15];
#pragma unroll
  for (int p = 0; p < 2; ++p) {
#pragma unroll
    for (int n = 0; n < 4; ++n) {
      float v = acc[2 * p][n][0];
#pragma unroll
      for (int i = 1; i < 4; ++i) v = fmaxf(v, acc[2 * p][n][i]);
#pragma unroll
      for (int i = 0; i < 4; ++i) v = fmaxf(v, acc[2 * p + 1][n][i]);
      v = fmaxf(v, __shfl_xor(v, 16));
      v = fmaxf(v, __shfl_xor(v, 32));
      if (lhi == 0)
        fg[(size_t)((grow >> 5) + wr * 2 + p) * 256 + y * 128 + wc * 64 + n * 16 + l15] =
            (f16)(v + bias[n]);
    }
  }

  if (WRITE_F2) {
    __syncthreads();
    f16* sF2 = sF1;
#pragma unroll
    for (int n = 0; n < 4; ++n) {
      int col = wc * 64 + n * 16 + l15;
#pragma unroll
      for (int m = 0; m < 4; ++m)
#pragma unroll
        for (int i = 0; i < 4; ++i) {
          int row = wr * 64 + m * 16 + lhi * 4 + i;
          sF2[row * 128 + col] = (f16)(acc[m][n][i] + bias[n]);
        }
    }
    __syncthreads();
#pragma unroll
    for (int ch = 0; ch < 8; ++ch) {
      int off = ch * 4096 + t * 16;
      int row = off >> 8, cb = off & 255;
      *(uint4*)((char*)f2 + (size_t)(blockIdx.x * 128 + row) * 512 + y * 256 + cb) =
          *(const uint4*)((const char*)sF2 + off);
    }
  }
}

// ---------------------------------------------------------------------------
// l34: fused L3+L4. 64 rows (2 groups) per block, 4 waves.
// Phase1 per slice j (128 cols of f3): K=256 GEMM vs W3bT -> BN2+relu -> sF3 (LDS)
// Phase2: acc2 += sF3-slice (as K-slice j) x W4T -> after 4 slices: group-max+b4
// LDS: sA 32K (f2 strip, full K) + sB 16K + sF3 16K = 64 KiB -> 2 blocks/CU
// ---------------------------------------------------------------------------
__global__ __launch_bounds__(256) void l34_kernel(const f16* __restrict__ f2,
                                                  const f16* __restrict__ W3bT,
                                                  const f16* __restrict__ W4T,
                                                  const float* __restrict__ g3,
                                                  const float* __restrict__ s2v,
                                                  const float* __restrict__ sh2v,
                                                  const float* __restrict__ b4,
                                                  float* __restrict__ out_x,
                                                  int gg0) {
  __shared__ __align__(16) char sMem[65536];
  char* sA  = sMem;            // 64 rows x 512B (f2, full K=256)
  char* sB  = sMem + 32768;    // 128 rows x 128B (W3bT k-tile)
  char* sF3 = sMem + 49152;    // 64 rows x 256B (f3 slice, f16)
  const int t = threadIdx.x, lane = t & 63, wid = t >> 6;
  const int wr = wid >> 1, wc = wid & 1;
  const int l15 = lane & 15, lhi = lane >> 4;
  const int row0 = blockIdx.x * 64;          // chunk-local f2 row base
  const int ggb = gg0 + (row0 >> 5);         // global group base (2 per block)

  // stage sA once: 8 rounds x 256 thr x 16B
#pragma unroll
  for (int rnd = 0; rnd < 8; ++rnd) {
    int o = rnd * 4096 + t * 16;
    int row = o >> 9, cb = o & 511;
    gl_lds16((const char*)f2 + (size_t)(row0 + row) * 512 + (cb ^ ((row & 7) << 4)), sA + o);
  }

  f32x4 acc2[2][12];
#pragma unroll
  for (int m = 0; m < 2; ++m)
#pragma unroll
    for (int n = 0; n < 12; ++n) acc2[m][n] = (f32x4){0.f, 0.f, 0.f, 0.f};

  for (int j = 0; j < 4; ++j) {
    f32x4 acc1[2][4];
#pragma unroll
    for (int m = 0; m < 2; ++m)
#pragma unroll
      for (int n = 0; n < 4; ++n) acc1[m][n] = (f32x4){0.f, 0.f, 0.f, 0.f};

    for (int kt = 0; kt < 4; ++kt) {
      // stage sB: W3bT rows [j*128, +128) x k [kt*64, +64) -> 16 KiB
#pragma unroll
      for (int rnd = 0; rnd < 4; ++rnd) {
        int o = rnd * 4096 + t * 16;
        int brow = o >> 7, bcol = o & 127;
        gl_lds16((const char*)W3bT + (size_t)(j * 128 + brow) * 512 + kt * 128 +
                     (bcol ^ ((brow & 7) << 4)),
                 sB + o);
      }
      __syncthreads();
#pragma unroll
      for (int ks = 0; ks < 2; ++ks) {
        f16x8 af[2], bf[4];
#pragma unroll
        for (int m = 0; m < 2; ++m) {
          int row = wr * 32 + m * 16 + l15;
          af[m] = *(const f16x8*)(sA + row * 512 +
                                  ((kt * 128 + ks * 64 + lhi * 16) ^ ((row & 7) << 4)));
        }
#pragma unroll
        for (int n = 0; n < 4; ++n) {
          int br = wc * 64 + n * 16 + l15;
          bf[n] = *(const f16x8*)(sB + br * 128 + ((ks * 64 + lhi * 16) ^ ((br & 7) << 4)));
        }
#pragma unroll
        for (int m = 0; m < 2; ++m)
#pragma unroll
          for (int n = 0; n < 4; ++n)
            acc1[m][n] = __builtin_amdgcn_mfma_f32_16x16x32_f16(af[m], bf[n], acc1[m][n], 0, 0, 0);
      }
      __syncthreads();
    }

    // phase1 epilogue: +g3, BN2, relu -> sF3 (f16, swizzled)
    {
      int grp = ggb + wr;
#pragma unroll
      for (int n = 0; n < 4; ++n) {
        int col = wc * 64 + n * 16 + l15;          // 0..127 within slice
        int gc = j * 128 + col;                    // global f3 col
        float s = s2v[gc], sh = sh2v[gc];
        float gv = g3[(size_t)grp * 512 + gc];
#pragma unroll
        for (int m = 0; m < 2; ++m)
#pragma unroll
          for (int i = 0; i < 4; ++i) {
            int row = wr * 32 + m * 16 + lhi * 4 + i;
            float v = (acc1[m][n][i] + gv) * s + sh;
            *(f16*)(sF3 + row * 256 + ((col * 2) ^ ((row & 7) << 4))) = (f16)fmaxf(v, 0.0f);
          }
      }
    }
    __syncthreads();

    // phase2: acc2 += sF3 (A, K-slice j) x W4T (B, reg-direct from L2)
#pragma unroll
    for (int ks = 0; ks < 4; ++ks) {
      f16x8 af[2];
#pragma unroll
      for (int m = 0; m < 2; ++m) {
        int row = wr * 32 + m * 16 + l15;
        af[m] = *(const f16x8*)(sF3 + row * 256 + ((ks * 64 + lhi * 16) ^ ((row & 7) << 4)));
      }
#pragma unroll
      for (int n = 0; n < 12; ++n) {
        int nrow = wc * 192 + n * 16 + l15;
        f16x8 bf = *(const f16x8*)((const char*)W4T + (size_t)nrow * 1024 +
                                   (j * 128 + ks * 32 + lhi * 8) * 2);
        acc2[0][n] = __builtin_amdgcn_mfma_f32_16x16x32_f16(af[0], bf, acc2[0][n], 0, 0, 0);
        acc2[1][n] = __builtin_amdgcn_mfma_f32_16x16x32_f16(af[1], bf, acc2[1][n], 0, 0, 0);
      }
    }
    // no barrier needed here: sF3/sB next overwrite is >=2 barriers away
  }

  // final: group-max + b4 -> out_x  (wave wr owns group ggb+wr entirely)
  size_t gout = (size_t)(ggb + wr) * ENC;
#pragma unroll
  for (int n = 0; n < 12; ++n) {
    float v = acc2[0][n][0];
#pragma unroll
    for (int i = 1; i < 4; ++i) v = fmaxf(v, acc2[0][n][i]);
#pragma unroll
    for (int i = 0; i < 4; ++i) v = fmaxf(v, acc2[1][n][i]);
    v = fmaxf(v, __shfl_xor(v, 16));
    v = fmaxf(v, __shfl_xor(v, 32));
    if (lhi == 0) {
      int col = wc * 192 + n * 16 + l15;
      out_x[gout + col] = v + b4[col];
    }
  }
}

// ---------------------------------------------------------------------------
// gemm128 (kept for g3 GEMM and pos GEMM)
// ---------------------------------------------------------------------------
template <int K, int EPI>
__global__ __launch_bounds__(256) void gemm128_kernel(const f16* __restrict__ A,
                                                      const f16* __restrict__ BT,
                                                      float* __restrict__ outF32,
                                                      const float* __restrict__ e0,
                                                      int NTOT) {
  __shared__ __align__(16) f16 sA[128 * 64];
  __shared__ __align__(16) f16 sB[128 * 64];
  const int t = threadIdx.x, lane = t & 63, wid = t >> 6;
  const int wrow = wid >> 1, wcol = wid & 1;
  const int l15 = lane & 15, lhi = lane >> 4;
  f32x4 acc[4][4];
#pragma unroll
  for (int m = 0; m < 4; ++m)
#pragma unroll
    for (int n = 0; n < 4; ++n) acc[m][n] = (f32x4){0.f, 0.f, 0.f, 0.f};

  const size_t arow0 = (size_t)blockIdx.x * 128;
  const int ncol0 = blockIdx.y * 128;
  const char* Ab = (const char*)A;
  const char* Bb = (const char*)BT;
  const int so = wid * 1024 + lane * 16;
  const int cb = so & 127;
  const int r0 = so >> 7;

  for (int kt = 0; kt < K; kt += 64) {
#pragma unroll
    for (int rnd = 0; rnd < 4; ++rnd) {
      int r = rnd * 32 + r0;
      int sw = (r & 7) << 4;
      gl_lds16(Ab + (arow0 + r) * (size_t)(K * 2) + kt * 2 + (cb ^ sw),
               (char*)sA + rnd * 4096 + wid * 1024);
      gl_lds16(Bb + (size_t)(ncol0 + r) * (K * 2) + kt * 2 + (cb ^ sw),
               (char*)sB + rnd * 4096 + wid * 1024);
    }
    __syncthreads();
#pragma unroll
    for (int ks = 0; ks < 2; ++ks) {
      f16x8 af[4], bf[4];
#pragma unroll
      for (int m = 0; m < 4; ++m) {
        int row = wrow * 64 + m * 16 + l15;
        int addr = row * 128 + ((ks * 64 + lhi * 16) ^ ((row & 7) << 4));
        af[m] = *(const f16x8*)((const char*)sA + addr);
      }
#pragma unroll
      for (int n = 0; n < 4; ++n) {
        int nrow = wcol * 64 + n * 16 + l15;
        int addr = nrow * 128 + ((ks * 64 + lhi * 16) ^ ((nrow & 7) << 4));
        bf[n] = *(const f16x8*)((const char*)sB + addr);
      }
#pragma unroll
      for (int m = 0; m < 4; ++m)
#pragma unroll
        for (int n = 0; n < 4; ++n)
          acc[m][n] = __builtin_amdgcn_mfma_f32_16x16x32_f16(af[m], bf[n], acc[m][n], 0, 0, 0);
    }
    __syncthreads();
  }

  if (EPI == 3) {
#pragma unroll
    for (int n = 0; n < 4; ++n) {
      int col = ncol0 + wcol * 64 + n * 16 + l15;
      float bias = e0[col];
#pragma unroll
      for (int m = 0; m < 4; ++m)
#pragma unroll
        for (int i = 0; i < 4; ++i) {
          size_t row = arow0 + wrow * 64 + m * 16 + lhi * 4 + i;
          outF32[row * NTOT + col] = acc[m][n][i] + bias;
        }
    }
  } else {  // EPI 4: pos out (strided [B,513,384])
#pragma unroll
    for (int n = 0; n < 4; ++n) {
      int col = ncol0 + wcol * 64 + n * 16 + l15;
      float bias = e0[col];
#pragma unroll
      for (int m = 0; m < 4; ++m)
#pragma unroll
        for (int i = 0; i < 4; ++i) {
          size_t row = arow0 + wrow * 64 + m * 16 + lhi * 4 + i;
          int b = (int)(row >> 9), g = (int)(row & 511);
          outF32[((size_t)b * 513 + 1 + g) * 384 + col] = acc[m][n][i] + bias;
        }
    }
  }
}

// ---------------------------------------------------------------------------
__global__ __launch_bounds__(256) void posh_kernel(const float* __restrict__ centers,
                                                   const float* __restrict__ Wp1,
                                                   const float* __restrict__ bp1,
                                                   f16* __restrict__ h) {
  int o = blockIdx.x * 256 + threadIdx.x;
  int row = o >> 7, c = o & 127;
  const float* ct = centers + (size_t)row * 3;
  float x = ct[0] * Wp1[c] + ct[1] * Wp1[128 + c] + ct[2] * Wp1[256 + c] + bp1[c];
  float u = 0.7978845608028654f * (x + 0.044715f * x * x * x);
  h[o] = (f16)(0.5f * x * (1.0f + tanhf(u)));
}

__global__ void cls_kernel(const float* __restrict__ cls_pos, float* __restrict__ out_pos) {
  out_pos[(size_t)blockIdx.x * (NG + 1) * ENC + threadIdx.x] = cls_pos[threadIdx.x];
}

// ---------------------------------------------------------------------------
extern "C" void kernel_launch(void* const* d_in, const int* in_sizes, int n_in,
                              void* d_out, int out_size, void* d_ws, size_t ws_size,
                              hipStream_t stream) {
  const float* pts = (const float*)d_in[0];
  const float* W1  = (const float*)d_in[1];
  const float* b1  = (const float*)d_in[2];
  const float* g1  = (const float*)d_in[3];
  const float* be1 = (const float*)d_in[4];
  const float* m1  = (const float*)d_in[5];
  const float* v1  = (const float*)d_in[6];
  const float* W2  = (const float*)d_in[7];
  const float* b2  = (const float*)d_in[8];
  const float* W3  = (const float*)d_in[9];
  const float* b3  = (const float*)d_in[10];
  const float* g2  = (const float*)d_in[11];
  const float* be2 = (const float*)d_in[12];
  const float* m2  = (const float*)d_in[13];
  const float* v2  = (const float*)d_in[14];
  const float* W4  = (const float*)d_in[15];
  const float* b4  = (const float*)d_in[16];
  const float* Wp1 = (const float*)d_in[17];
  const float* bp1 = (const float*)d_in[18];
  const float* Wp2 = (const float*)d_in[19];
  const float* bp2 = (const float*)d_in[20];
  const float* cls = (const float*)d_in[21];

  float* out_x   = (float*)d_out;
  float* out_pos = out_x + (size_t)NB * NG * ENC;

  char* w = (char*)d_ws;
  auto alloc = [&](size_t bytes) {
    char* p = w;
    w += (bytes + 255) & ~(size_t)255;
    return p;
  };
  float* centers = (float*)alloc((size_t)NB * NG * 3 * 4);
  int*   knn     = (int*)alloc((size_t)NB * NG * NM * 4);
  f16*   W2T     = (f16*)alloc(32768 * 2);
  f16*   W3aT    = (f16*)alloc(131072 * 2);
  f16*   W3bT    = (f16*)alloc(131072 * 2);
  f16*   W4T     = (f16*)alloc(196608 * 2);
  f16*   Wp2T    = (f16*)alloc(49152 * 2);
  float* s1      = (float*)alloc(128 * 4);
  float* sh1     = (float*)alloc(128 * 4);
  float* s2      = (float*)alloc(512 * 4);
  float* sh2     = (float*)alloc(512 * 4);
  f16*   fg      = (f16*)alloc((size_t)8192 * 256 * 2);
  float* g3      = (float*)alloc((size_t)8192 * 512 * 4);
  f16*   h       = (f16*)alloc((size_t)8192 * 128 * 2);
  size_t fixed = (size_t)(w - (char*)d_ws);
  const size_t f2_full = (size_t)NROWS * 256 * 2;   // 128 MiB

  quant_kernel<<<dim3(2115), dim3(256), 0, stream>>>(W2, W3, W4, Wp2, b1, g1, be1, m1, v1,
                                                     g2, be2, m2, v2, W2T, W3aT, W3bT, W4T,
                                                     Wp2T, s1, sh1, s2, sh2);
  fps_kernel<<<dim3(NB), dim3(512), 0, stream>>>(pts, centers);
  knn_kernel<<<dim3(NB * NG), dim3(256), 0, stream>>>(pts, centers, knn);

  if (ws_size >= fixed + f2_full + 4096) {
    // f2 full; single fused l34 pass (no f3 anywhere)
    f16* f2 = (f16*)alloc(f2_full);
    l2f_kernel<1><<<dim3(2048, 2), dim3(256), 0, stream>>>(pts, centers, knn, W1, s1, sh1,
                                                           W2T, b2, fg, f2, 0);
    gemm128_kernel<256, 3><<<dim3(64, 4), dim3(256), 0, stream>>>(fg, W3aT, g3, b3, 512);
    l34_kernel<<<dim3(NROWS / 64), dim3(256), 0, stream>>>(f2, W3bT, W4T, g3, s2, sh2, b4,
                                                           out_x, 0);
  } else {
    // LOW: fg prepass + 8 chunks of {l2f-write, l34}
    f16* f2c = (f16*)alloc((size_t)32768 * 256 * 2);   // 16 MiB
    l2f_kernel<0><<<dim3(2048, 2), dim3(256), 0, stream>>>(pts, centers, knn, W1, s1, sh1,
                                                           W2T, b2, fg, nullptr, 0);
    gemm128_kernel<256, 3><<<dim3(64, 4), dim3(256), 0, stream>>>(fg, W3aT, g3, b3, 512);
    for (int c = 0; c < 8; ++c) {
      l2f_kernel<1><<<dim3(256, 2), dim3(256), 0, stream>>>(pts, centers, knn, W1, s1, sh1,
                                                            W2T, b2, fg, f2c, c * 32768);
      l34_kernel<<<dim3(512), dim3(256), 0, stream>>>(f2c, W3bT, W4T, g3, s2, sh2, b4,
                                                      out_x, c * 1024);
    }
  }

  posh_kernel<<<dim3(4096), dim3(256), 0, stream>>>(centers, Wp1, bp1, h);
  gemm128_kernel<128, 4><<<dim3(64, 3), dim3(256), 0, stream>>>(h, Wp2T, out_pos, bp2, 384);
  cls_kernel<<<dim3(NB), dim3(ENC), 0, stream>>>(cls, out_pos);
}

// Round 8
// 1185.088 us; speedup vs baseline: 1.2499x; 1.2499x over previous
//
#include <hip/hip_runtime.h>

typedef _Float16 f16;
typedef _Float16 f16x8 __attribute__((ext_vector_type(8)));
typedef float    f32x4 __attribute__((ext_vector_type(4)));

#define NB   16
#define NP   8192
#define NG   512
#define NM   32
#define ENC  384
#define NROWS (NB * NG * NM)      // 262144 total rows

// ---------------------------------------------------------------------------
// helpers
// ---------------------------------------------------------------------------
__device__ __forceinline__ void gl_lds16(const void* g, void* l) {
  __builtin_amdgcn_global_load_lds((const __attribute__((address_space(1))) unsigned int*)g,
                                   (__attribute__((address_space(3))) unsigned int*)l, 16, 0, 0);
}

__device__ __forceinline__ unsigned long long kmax(unsigned long long a, unsigned long long b) {
  return a > b ? a : b;
}
__device__ __forceinline__ unsigned long long kmin(unsigned long long a, unsigned long long b) {
  return a < b ? a : b;
}

template <int CTRL>
__device__ __forceinline__ unsigned long long dpp_kmax(unsigned long long k) {
  int lo = (int)(unsigned)(k & 0xFFFFFFFFull);
  int hi = (int)(unsigned)(k >> 32);
  int olo = __builtin_amdgcn_update_dpp(lo, lo, CTRL, 0xF, 0xF, false);
  int ohi = __builtin_amdgcn_update_dpp(hi, hi, CTRL, 0xF, 0xF, false);
  unsigned long long o = ((unsigned long long)(unsigned)ohi << 32) | (unsigned)olo;
  return kmax(k, o);
}
template <int CTRL>
__device__ __forceinline__ unsigned long long dpp_kmin(unsigned long long k) {
  int lo = (int)(unsigned)(k & 0xFFFFFFFFull);
  int hi = (int)(unsigned)(k >> 32);
  int olo = __builtin_amdgcn_update_dpp(lo, lo, CTRL, 0xF, 0xF, false);
  int ohi = __builtin_amdgcn_update_dpp(hi, hi, CTRL, 0xF, 0xF, false);
  unsigned long long o = ((unsigned long long)(unsigned)ohi << 32) | (unsigned)olo;
  return kmin(k, o);
}
__device__ __forceinline__ unsigned long long swz16_kmax(unsigned long long k) {
  int lo = (int)(unsigned)(k & 0xFFFFFFFFull);
  int hi = (int)(unsigned)(k >> 32);
  int olo = __builtin_amdgcn_ds_swizzle(lo, 0x401F);
  int ohi = __builtin_amdgcn_ds_swizzle(hi, 0x401F);
  unsigned long long o = ((unsigned long long)(unsigned)ohi << 32) | (unsigned)olo;
  return kmax(k, o);
}
__device__ __forceinline__ unsigned long long swz16_kmin(unsigned long long k) {
  int lo = (int)(unsigned)(k & 0xFFFFFFFFull);
  int hi = (int)(unsigned)(k >> 32);
  int olo = __builtin_amdgcn_ds_swizzle(lo, 0x401F);
  int ohi = __builtin_amdgcn_ds_swizzle(hi, 0x401F);
  unsigned long long o = ((unsigned long long)(unsigned)ohi << 32) | (unsigned)olo;
  return kmin(k, o);
}

#define DPP_QUAD_XOR1 0xB1
#define DPP_QUAD_XOR2 0x4E
#define DPP_HALF_MIRR 0x141
#define DPP_ROW_MIRR  0x140

// ---------------------------------------------------------------------------
// FPS v3 (round-3 exact, best measured: 468us): scalar distances (bitwise-
// exact vs reference), integrated in-thread argmax chain, packed-u64 DPP
// reduce, LDS point mirror for uniform centroid broadcast, 1 barrier/step.
// ---------------------------------------------------------------------------
__global__ __launch_bounds__(512) void fps_kernel(const float* __restrict__ pts,
                                                  float* __restrict__ centers) {
#pragma clang fp contract(off)
  const int b = blockIdx.x;
  const float* pb = pts + (size_t)b * NP * 3;
  const int t = threadIdx.x;
  const int lane = t & 63, wid = t >> 6;     // 8 waves
  __shared__ float spx[NP], spy[NP], spz[NP];          // 96 KiB
  __shared__ unsigned long long swk[2][16];
  float px[16], py[16], pz[16], dd[16];
#pragma unroll
  for (int i = 0; i < 16; ++i) {
    int idx = t + i * 512;
    float x = pb[idx * 3 + 0], y = pb[idx * 3 + 1], z = pb[idx * 3 + 2];
    px[i] = x; py[i] = y; pz[i] = z; dd[i] = 1e10f;
    spx[idx] = x; spy[idx] = y; spz[idx] = z;
  }
  __syncthreads();
  float cx = spx[0], cy = spy[0], cz = spz[0];
  for (int g = 0; g < NG; ++g) {
    if (t == 0) {
      float* c = centers + ((size_t)b * NG + g) * 3;
      c[0] = cx; c[1] = cy; c[2] = cz;
    }
    float best = -1.0f; int bslot = 0;
#pragma unroll
    for (int i = 0; i < 16; ++i) {
      float dx = __fsub_rn(px[i], cx);
      float dy = __fsub_rn(py[i], cy);
      float dz = __fsub_rn(pz[i], cz);
      float d  = __fadd_rn(__fadd_rn(__fmul_rn(dx, dx), __fmul_rn(dy, dy)), __fmul_rn(dz, dz));
      dd[i] = fminf(dd[i], d);
      if (dd[i] > best) { best = dd[i]; bslot = i; }
    }
    int bidx = t + bslot * 512;
    unsigned long long key =
        ((unsigned long long)__float_as_uint(best) << 13) | (unsigned)(8191 - bidx);
    key = dpp_kmax<DPP_QUAD_XOR1>(key);
    key = dpp_kmax<DPP_QUAD_XOR2>(key);
    key = dpp_kmax<DPP_HALF_MIRR>(key);
    key = dpp_kmax<DPP_ROW_MIRR>(key);
    key = swz16_kmax(key);
    const int p = g & 1;
    if ((lane & 31) == 0) swk[p][wid * 2 + (lane >> 5)] = key;   // 16 entries
    __syncthreads();
    unsigned long long k2 = swk[p][lane & 15];
    k2 = dpp_kmax<DPP_QUAD_XOR1>(k2);
    k2 = dpp_kmax<DPP_QUAD_XOR2>(k2);
    k2 = dpp_kmax<DPP_HALF_MIRR>(k2);
    k2 = dpp_kmax<DPP_ROW_MIRR>(k2);
    int widx = 8191 - (int)(k2 & 0x1FFFull);
    cx = spx[widx]; cy = spy[widx]; cz = spz[widx];   // uniform broadcast read
  }
}

// ---------------------------------------------------------------------------
// kNN v3 (unchanged)
// ---------------------------------------------------------------------------
__global__ __launch_bounds__(256) void knn_kernel(const float* __restrict__ pts,
                                                  const float* __restrict__ centers,
                                                  int* __restrict__ knn_idx) {
#pragma clang fp contract(off)
  const int gg = blockIdx.x;
  const int b = gg >> 9;
  const float* pb = pts + (size_t)b * NP * 3;
  const float* c = centers + (size_t)gg * 3;
  const float cx = c[0], cy = c[1], cz = c[2];
  __shared__ unsigned long long swk[2][8];
  const int t = threadIdx.x, lane = t & 63, wid = t >> 6;
  float d[32];
  float lmin = 3e38f; int lidx = 0;
#pragma unroll
  for (int i = 0; i < 32; ++i) {
    int idx = i * 256 + t;
    float dx = __fsub_rn(cx, pb[idx * 3 + 0]);
    float dy = __fsub_rn(cy, pb[idx * 3 + 1]);
    float dz = __fsub_rn(cz, pb[idx * 3 + 2]);
    d[i] = __fadd_rn(__fadd_rn(__fmul_rn(dx, dx), __fmul_rn(dy, dy)), __fmul_rn(dz, dz));
    if (d[i] < lmin) { lmin = d[i]; lidx = idx; }
  }
  int* outp = knn_idx + (size_t)gg * NM;
  for (int r = 0; r < NM; ++r) {
    unsigned long long key =
        ((unsigned long long)__float_as_uint(lmin) << 13) | (unsigned)lidx;
    key = dpp_kmin<DPP_QUAD_XOR1>(key);
    key = dpp_kmin<DPP_QUAD_XOR2>(key);
    key = dpp_kmin<DPP_HALF_MIRR>(key);
    key = dpp_kmin<DPP_ROW_MIRR>(key);
    key = swz16_kmin(key);
    const int p = r & 1;
    if ((lane & 31) == 0) swk[p][wid * 2 + (lane >> 5)] = key;
    __syncthreads();
    unsigned long long k2 = swk[p][lane & 7];
    k2 = dpp_kmin<DPP_QUAD_XOR1>(k2);
    k2 = dpp_kmin<DPP_QUAD_XOR2>(k2);
    k2 = dpp_kmin<DPP_HALF_MIRR>(k2);
    int i0 = (int)(k2 & 0x1FFFull);
    if (t == 0) outp[r] = i0;
    if ((i0 & 255) == t) {
      int slot = i0 >> 8;
      lmin = 3e38f; lidx = 0;
#pragma unroll
      for (int i = 0; i < 32; ++i) {
        float di = (i == slot) ? 3e38f : d[i];
        d[i] = di;
        if (di < lmin) { lmin = di; lidx = i * 256 + t; }
      }
    }
  }
}

// ---------------------------------------------------------------------------
// quant: f16 weight transposes + BN scale/shift precompute
// ---------------------------------------------------------------------------
__global__ void quant_kernel(const float* __restrict__ W2, const float* __restrict__ W3,
                             const float* __restrict__ W4, const float* __restrict__ Wp2,
                             const float* __restrict__ b1, const float* __restrict__ g1,
                             const float* __restrict__ be1, const float* __restrict__ m1,
                             const float* __restrict__ v1, const float* __restrict__ g2,
                             const float* __restrict__ be2, const float* __restrict__ m2,
                             const float* __restrict__ v2,
                             f16* __restrict__ W2T, f16* __restrict__ W3aT,
                             f16* __restrict__ W3bT, f16* __restrict__ W4T,
                             f16* __restrict__ Wp2T,
                             float* __restrict__ s1, float* __restrict__ sh1,
                             float* __restrict__ s2, float* __restrict__ sh2) {
  int i = blockIdx.x * 256 + threadIdx.x;
  if (i < 32768) { int n = i >> 7, k = i & 127; W2T[i] = (f16)W2[(size_t)k * 256 + n]; return; }
  i -= 32768;
  if (i < 131072) { int n = i >> 8, k = i & 255; W3aT[i] = (f16)W3[(size_t)k * 512 + n]; return; }
  i -= 131072;
  if (i < 131072) { int n = i >> 8, k = i & 255; W3bT[i] = (f16)W3[(size_t)(256 + k) * 512 + n]; return; }
  i -= 131072;
  if (i < 196608) { int n = i >> 9, k = i & 511; W4T[i] = (f16)W4[(size_t)k * 384 + n]; return; }
  i -= 196608;
  if (i < 49152) { int n = i >> 7, k = i & 127; Wp2T[i] = (f16)Wp2[(size_t)k * 384 + n]; return; }
  i -= 49152;
  if (i < 128) {
    float s = g1[i] * rsqrtf(v1[i] + 1e-5f);
    s1[i] = s; sh1[i] = (b1[i] - m1[i]) * s + be1[i];
    return;
  }
  i -= 128;
  if (i < 512) {
    float s = g2[i] * rsqrtf(v2[i] + 1e-5f);
    s2[i] = s; sh2[i] = be2[i] - m2[i] * s;
    return;
  }
}

// ---------------------------------------------------------------------------
// l2f: fused gather + L1 MLP (in LDS) + L2 GEMM + fg epilogue (+ f2 write)
// ---------------------------------------------------------------------------
template <int WRITE_F2>
__global__ __launch_bounds__(256) void l2f_kernel(const float* __restrict__ pts,
                                                  const float* __restrict__ centers,
                                                  const int* __restrict__ knn_idx,
                                                  const float* __restrict__ W1,
                                                  const float* __restrict__ s1,
                                                  const float* __restrict__ sh1,
                                                  const f16* __restrict__ W2T,
                                                  const float* __restrict__ b2,
                                                  f16* __restrict__ fg,
                                                  f16* __restrict__ f2, int grow0) {
  __shared__ __align__(16) f16 sF1[128 * 128];
  __shared__ float snb[128][3];
  const int t = threadIdx.x, lane = t & 63, wid = t >> 6;
  const int wr = wid >> 1, wc = wid & 1;
  const int l15 = lane & 15, lhi = lane >> 4;
  const int grow = grow0 + blockIdx.x * 128;
  const int y = blockIdx.y;

  if (t < 128) {
    int row = grow + t;
    int gg = row >> 5;
    int b = gg >> 9;
    int idx = knn_idx[(size_t)gg * NM + (row & 31)];
    const float* p = pts + ((size_t)b * NP + idx) * 3;
    const float* c = centers + (size_t)gg * 3;
    snb[t][0] = p[0] - c[0];
    snb[t][1] = p[1] - c[1];
    snb[t][2] = p[2] - c[2];
  }
  __syncthreads();
  {
    int row = t >> 1, c0 = (t & 1) * 64;
    float nx = snb[row][0], ny = snb[row][1], nz = snb[row][2];
    int sw = (row & 7) << 4;
#pragma unroll
    for (int cc = 0; cc < 64; cc += 8) {
      f16x8 v;
#pragma unroll
      for (int j = 0; j < 8; ++j) {
        int c = c0 + cc + j;
        float a = nx * W1[c] + ny * W1[128 + c] + nz * W1[256 + c];
        a = a * s1[c] + sh1[c];
        v[j] = (f16)fmaxf(a, 0.0f);
      }
      *(f16x8*)((char*)sF1 + row * 256 + (((c0 + cc) * 2) ^ sw)) = v;
    }
  }
  __syncthreads();

  f32x4 acc[4][4];
#pragma unroll
  for (int m = 0; m < 4; ++m)
#pragma unroll
    for (int n = 0; n < 4; ++n) acc[m][n] = (f32x4){0.f, 0.f, 0.f, 0.f};

  const f16* Wb = W2T + (size_t)(y * 128) * 128;
#pragma unroll
  for (int ks = 0; ks < 4; ++ks) {
    f16x8 af[4], bf[4];
#pragma unroll
    for (int m = 0; m < 4; ++m) {
      int row = wr * 64 + m * 16 + l15;
      af[m] = *(const f16x8*)((const char*)sF1 + row * 256 + ((ks * 64 + lhi * 16) ^ ((row & 7) << 4)));
    }
#pragma unroll
    for (int n = 0; n < 4; ++n) {
      int nr = wc * 64 + n * 16 + l15;
      bf[n] = *(const f16x8*)(Wb + (size_t)nr * 128 + ks * 32 + lhi * 8);
    }
#pragma unroll
    for (int m = 0; m < 4; ++m)
#pragma unroll
      for (int n = 0; n < 4; ++n)
        acc[m][n] = __builtin_amdgcn_mfma_f32_16x16x32_f16(af[m], bf[n], acc[m][n], 0, 0, 0);
  }

  float bias[4];
#pragma unroll
  for (int n = 0; n < 4; ++n) bias[n] = b2[y * 128 + wc * 64 + n * 16 + l15];
#pragma unroll
  for (int p = 0; p < 2; ++p) {
#pragma unroll
    for (int n = 0; n < 4; ++n) {
      float v = acc[2 * p][n][0];
#pragma unroll
      for (int i = 1; i < 4; ++i) v = fmaxf(v, acc[2 * p][n][i]);
#pragma unroll
      for (int i = 0; i < 4; ++i) v = fmaxf(v, acc[2 * p + 1][n][i]);
      v = fmaxf(v, __shfl_xor(v, 16));
      v = fmaxf(v, __shfl_xor(v, 32));
      if (lhi == 0)
        fg[(size_t)((grow >> 5) + wr * 2 + p) * 256 + y * 128 + wc * 64 + n * 16 + l15] =
            (f16)(v + bias[n]);
    }
  }

  if (WRITE_F2) {
    __syncthreads();
    f16* sF2 = sF1;
#pragma unroll
    for (int n = 0; n < 4; ++n) {
      int col = wc * 64 + n * 16 + l15;
#pragma unroll
      for (int m = 0; m < 4; ++m)
#pragma unroll
        for (int i = 0; i < 4; ++i) {
          int row = wr * 64 + m * 16 + lhi * 4 + i;
          sF2[row * 128 + col] = (f16)(acc[m][n][i] + bias[n]);
        }
    }
    __syncthreads();
#pragma unroll
    for (int ch = 0; ch < 8; ++ch) {
      int off = ch * 4096 + t * 16;
      int row = off >> 8, cb = off & 255;
      *(uint4*)((char*)f2 + (size_t)(blockIdx.x * 128 + row) * 512 + y * 256 + cb) =
          *(const uint4*)((const char*)sF2 + off);
    }
  }
}

// ---------------------------------------------------------------------------
// gemm128: 128x128 tile, BK=64, 4 waves, global_load_lds + XOR swizzle
// EPI 1: L3  (+g3 global, *s2 +sh2, relu) -> f16
// EPI 2: L4  group-max +b4 -> out_x f32
// EPI 3: f32 out + bias (g3 gemm)
// EPI 4: pos out (strided [B,513,384]) + bias
// ---------------------------------------------------------------------------
template <int K, int EPI>
__global__ __launch_bounds__(256) void gemm128_kernel(const f16* __restrict__ A,
                                                      const f16* __restrict__ BT,
                                                      float* __restrict__ outF32,
                                                      f16* __restrict__ outF16,
                                                      const float* __restrict__ e0,
                                                      const float* __restrict__ e1,
                                                      const float* __restrict__ e2,
                                                      int NTOT, int gg0) {
  __shared__ __align__(16) f16 sA[128 * 64];
  __shared__ __align__(16) f16 sB[128 * 64];
  const int t = threadIdx.x, lane = t & 63, wid = t >> 6;
  const int wrow = wid >> 1, wcol = wid & 1;
  const int l15 = lane & 15, lhi = lane >> 4;
  f32x4 acc[4][4];
#pragma unroll
  for (int m = 0; m < 4; ++m)
#pragma unroll
    for (int n = 0; n < 4; ++n) acc[m][n] = (f32x4){0.f, 0.f, 0.f, 0.f};

  const size_t arow0 = (size_t)blockIdx.x * 128;
  const int ncol0 = blockIdx.y * 128;
  const char* Ab = (const char*)A;
  const char* Bb = (const char*)BT;
  const int so = wid * 1024 + lane * 16;
  const int cb = so & 127;
  const int r0 = so >> 7;

  for (int kt = 0; kt < K; kt += 64) {
#pragma unroll
    for (int rnd = 0; rnd < 4; ++rnd) {
      int r = rnd * 32 + r0;
      int sw = (r & 7) << 4;
      gl_lds16(Ab + (arow0 + r) * (size_t)(K * 2) + kt * 2 + (cb ^ sw),
               (char*)sA + rnd * 4096 + wid * 1024);
      gl_lds16(Bb + (size_t)(ncol0 + r) * (K * 2) + kt * 2 + (cb ^ sw),
               (char*)sB + rnd * 4096 + wid * 1024);
    }
    __syncthreads();
#pragma unroll
    for (int ks = 0; ks < 2; ++ks) {
      f16x8 af[4], bf[4];
#pragma unroll
      for (int m = 0; m < 4; ++m) {
        int row = wrow * 64 + m * 16 + l15;
        int addr = row * 128 + ((ks * 64 + lhi * 16) ^ ((row & 7) << 4));
        af[m] = *(const f16x8*)((const char*)sA + addr);
      }
#pragma unroll
      for (int n = 0; n < 4; ++n) {
        int nrow = wcol * 64 + n * 16 + l15;
        int addr = nrow * 128 + ((ks * 64 + lhi * 16) ^ ((nrow & 7) << 4));
        bf[n] = *(const f16x8*)((const char*)sB + addr);
      }
#pragma unroll
      for (int m = 0; m < 4; ++m)
#pragma unroll
        for (int n = 0; n < 4; ++n)
          acc[m][n] = __builtin_amdgcn_mfma_f32_16x16x32_f16(af[m], bf[n], acc[m][n], 0, 0, 0);
    }
    __syncthreads();
  }

  if (EPI == 1) {
#pragma unroll
    for (int n = 0; n < 4; ++n) {
      int col = ncol0 + wcol * 64 + n * 16 + l15;
      float s = e1[col], sh = e2[col];
#pragma unroll
      for (int m = 0; m < 4; ++m) {
        int grp = gg0 + blockIdx.x * 4 + wrow * 2 + (m >> 1);
        float gv = e0[(size_t)grp * 512 + col];
#pragma unroll
        for (int i = 0; i < 4; ++i) {
          size_t row = arow0 + wrow * 64 + m * 16 + lhi * 4 + i;
          float v = (acc[m][n][i] + gv) * s + sh;
          outF16[row * NTOT + col] = (f16)fmaxf(v, 0.0f);
        }
      }
    }
  } else if (EPI == 2) {
#pragma unroll
    for (int pr = 0; pr < 2; ++pr) {
      size_t gg_glob = (size_t)gg0 + blockIdx.x * 4 + wrow * 2 + pr;
#pragma unroll
      for (int n = 0; n < 4; ++n) {
        float v = acc[2 * pr][n][0];
#pragma unroll
        for (int i = 1; i < 4; ++i) v = fmaxf(v, acc[2 * pr][n][i]);
#pragma unroll
        for (int i = 0; i < 4; ++i) v = fmaxf(v, acc[2 * pr + 1][n][i]);
        v = fmaxf(v, __shfl_xor(v, 16));
        v = fmaxf(v, __shfl_xor(v, 32));
        if (lhi == 0) {
          int col = ncol0 + wcol * 64 + n * 16 + l15;
          outF32[gg_glob * ENC + col] = v + e0[col];
        }
      }
    }
  } else if (EPI == 3) {
#pragma unroll
    for (int n = 0; n < 4; ++n) {
      int col = ncol0 + wcol * 64 + n * 16 + l15;
      float bias = e0[col];
#pragma unroll
      for (int m = 0; m < 4; ++m)
#pragma unroll
        for (int i = 0; i < 4; ++i) {
          size_t row = arow0 + wrow * 64 + m * 16 + lhi * 4 + i;
          outF32[row * NTOT + col] = acc[m][n][i] + bias;
        }
    }
  } else {  // EPI 4: pos out (strided [B,513,384])
#pragma unroll
    for (int n = 0; n < 4; ++n) {
      int col = ncol0 + wcol * 64 + n * 16 + l15;
      float bias = e0[col];
#pragma unroll
      for (int m = 0; m < 4; ++m)
#pragma unroll
        for (int i = 0; i < 4; ++i) {
          size_t row = arow0 + wrow * 64 + m * 16 + lhi * 4 + i;
          int b = (int)(row >> 9), g = (int)(row & 511);
          outF32[((size_t)b * 513 + 1 + g) * 384 + col] = acc[m][n][i] + bias;
        }
    }
  }
}

// ---------------------------------------------------------------------------
__global__ __launch_bounds__(256) void posh_kernel(const float* __restrict__ centers,
                                                   const float* __restrict__ Wp1,
                                                   const float* __restrict__ bp1,
                                                   f16* __restrict__ h) {
  int o = blockIdx.x * 256 + threadIdx.x;
  int row = o >> 7, c = o & 127;
  const float* ct = centers + (size_t)row * 3;
  float x = ct[0] * Wp1[c] + ct[1] * Wp1[128 + c] + ct[2] * Wp1[256 + c] + bp1[c];
  float u = 0.7978845608028654f * (x + 0.044715f * x * x * x);
  h[o] = (f16)(0.5f * x * (1.0f + tanhf(u)));
}

__global__ void cls_kernel(const float* __restrict__ cls_pos, float* __restrict__ out_pos) {
  out_pos[(size_t)blockIdx.x * (NG + 1) * ENC + threadIdx.x] = cls_pos[threadIdx.x];
}

// ---------------------------------------------------------------------------
extern "C" void kernel_launch(void* const* d_in, const int* in_sizes, int n_in,
                              void* d_out, int out_size, void* d_ws, size_t ws_size,
                              hipStream_t stream) {
  const float* pts = (const float*)d_in[0];
  const float* W1  = (const float*)d_in[1];
  const float* b1  = (const float*)d_in[2];
  const float* g1  = (const float*)d_in[3];
  const float* be1 = (const float*)d_in[4];
  const float* m1  = (const float*)d_in[5];
  const float* v1  = (const float*)d_in[6];
  const float* W2  = (const float*)d_in[7];
  const float* b2  = (const float*)d_in[8];
  const float* W3  = (const float*)d_in[9];
  const float* b3  = (const float*)d_in[10];
  const float* g2  = (const float*)d_in[11];
  const float* be2 = (const float*)d_in[12];
  const float* m2  = (const float*)d_in[13];
  const float* v2  = (const float*)d_in[14];
  const float* W4  = (const float*)d_in[15];
  const float* b4  = (const float*)d_in[16];
  const float* Wp1 = (const float*)d_in[17];
  const float* bp1 = (const float*)d_in[18];
  const float* Wp2 = (const float*)d_in[19];
  const float* bp2 = (const float*)d_in[20];
  const float* cls = (const float*)d_in[21];

  float* out_x   = (float*)d_out;
  float* out_pos = out_x + (size_t)NB * NG * ENC;

  char* w = (char*)d_ws;
  auto alloc = [&](size_t bytes) {
    char* p = w;
    w += (bytes + 255) & ~(size_t)255;
    return p;
  };
  float* centers = (float*)alloc((size_t)NB * NG * 3 * 4);
  int*   knn     = (int*)alloc((size_t)NB * NG * NM * 4);
  f16*   W2T     = (f16*)alloc(32768 * 2);
  f16*   W3aT    = (f16*)alloc(131072 * 2);
  f16*   W3bT    = (f16*)alloc(131072 * 2);
  f16*   W4T     = (f16*)alloc(196608 * 2);
  f16*   Wp2T    = (f16*)alloc(49152 * 2);
  float* s1      = (float*)alloc(128 * 4);
  float* sh1     = (float*)alloc(128 * 4);
  float* s2      = (float*)alloc(512 * 4);
  float* sh2     = (float*)alloc(512 * 4);
  f16*   fg      = (f16*)alloc((size_t)8192 * 256 * 2);
  float* g3      = (float*)alloc((size_t)8192 * 512 * 4);
  f16*   h       = (f16*)alloc((size_t)8192 * 128 * 2);
  size_t fixed = (size_t)(w - (char*)d_ws);
  const size_t f2_full = (size_t)NROWS * 256 * 2;   // 128 MiB
  const size_t f3_full = (size_t)NROWS * 512 * 2;   // 256 MiB

  quant_kernel<<<dim3(2115), dim3(256), 0, stream>>>(W2, W3, W4, Wp2, b1, g1, be1, m1, v1,
                                                     g2, be2, m2, v2, W2T, W3aT, W3bT, W4T,
                                                     Wp2T, s1, sh1, s2, sh2);
  fps_kernel<<<dim3(NB), dim3(512), 0, stream>>>(pts, centers);
  knn_kernel<<<dim3(NB * NG), dim3(256), 0, stream>>>(pts, centers, knn);

  if (ws_size >= fixed + f2_full + f3_full / 4 + 4096) {
    // MID (proven): f2 full; f3 in 4 LLC-resident chunks (64 MiB each)
    f16* f2  = (f16*)alloc(f2_full);
    f16* f3c = (f16*)alloc(f3_full / 4);
    l2f_kernel<1><<<dim3(2048, 2), dim3(256), 0, stream>>>(pts, centers, knn, W1, s1, sh1,
                                                           W2T, b2, fg, f2, 0);
    gemm128_kernel<256, 3><<<dim3(64, 4), dim3(256), 0, stream>>>(
        fg, W3aT, g3, nullptr, b3, nullptr, nullptr, 512, 0);
    for (int c = 0; c < 4; ++c) {
      gemm128_kernel<256, 1><<<dim3(512, 4), dim3(256), 0, stream>>>(
          f2 + (size_t)c * 65536 * 256, W3bT, nullptr, f3c, g3, s2, sh2, 512, c * 2048);
      gemm128_kernel<512, 2><<<dim3(512, 3), dim3(256), 0, stream>>>(
          f3c, W4T, out_x, nullptr, b4, nullptr, nullptr, 384, c * 2048);
    }
  } else {
    // LOW: fg prepass + 8 chunks of {l2f-write, L3, L4}
    f16* f2c = (f16*)alloc((size_t)32768 * 256 * 2);
    f16* f3c = (f16*)alloc((size_t)32768 * 512 * 2);
    l2f_kernel<0><<<dim3(2048, 2), dim3(256), 0, stream>>>(pts, centers, knn, W1, s1, sh1,
                                                           W2T, b2, fg, nullptr, 0);
    gemm128_kernel<256, 3><<<dim3(64, 4), dim3(256), 0, stream>>>(
        fg, W3aT, g3, nullptr, b3, nullptr, nullptr, 512, 0);
    for (int c = 0; c < 8; ++c) {
      l2f_kernel<1><<<dim3(256, 2), dim3(256), 0, stream>>>(pts, centers, knn, W1, s1, sh1,
                                                            W2T, b2, fg, f2c, c * 32768);
      gemm128_kernel<256, 1><<<dim3(256, 4), dim3(256), 0, stream>>>(
          f2c, W3bT, nullptr, f3c, g3, s2, sh2, 512, c * 1024);
      gemm128_kernel<512, 2><<<dim3(256, 3), dim3(256), 0, stream>>>(
          f3c, W4T, out_x, nullptr, b4, nullptr, nullptr, 384, c * 1024);
    }
  }

  posh_kernel<<<dim3(4096), dim3(256), 0, stream>>>(centers, Wp1, bp1, h);
  gemm128_kernel<128, 4><<<dim3(64, 3), dim3(256), 0, stream>>>(
      h, Wp2T, out_pos, nullptr, bp2, nullptr, nullptr, 384, 0);
  cls_kernel<<<dim3(NB), dim3(ENC), 0, stream>>>(cls, out_pos);
}

// Round 9
// 1123.953 us; speedup vs baseline: 1.3179x; 1.0544x over previous
//
#include <hip/hip_runtime.h>

typedef _Float16 f16;
typedef _Float16 f16x8 __attribute__((ext_vector_type(8)));
typedef float    f32x4 __attribute__((ext_vector_type(4)));

#define NB   16
#define NP   8192
#define NG   512
#define NM   32
#define ENC  384
#define NROWS (NB * NG * NM)      // 262144 total rows

// ---------------------------------------------------------------------------
// helpers
// ---------------------------------------------------------------------------
__device__ __forceinline__ void gl_lds16(const void* g, void* l) {
  __builtin_amdgcn_global_load_lds((const __attribute__((address_space(1))) unsigned int*)g,
                                   (__attribute__((address_space(3))) unsigned int*)l, 16, 0, 0);
}

__device__ __forceinline__ unsigned long long kmax(unsigned long long a, unsigned long long b) {
  return a > b ? a : b;
}
__device__ __forceinline__ unsigned long long kmin(unsigned long long a, unsigned long long b) {
  return a < b ? a : b;
}

template <int CTRL>
__device__ __forceinline__ unsigned long long dpp_kmax(unsigned long long k) {
  int lo = (int)(unsigned)(k & 0xFFFFFFFFull);
  int hi = (int)(unsigned)(k >> 32);
  int olo = __builtin_amdgcn_update_dpp(lo, lo, CTRL, 0xF, 0xF, false);
  int ohi = __builtin_amdgcn_update_dpp(hi, hi, CTRL, 0xF, 0xF, false);
  unsigned long long o = ((unsigned long long)(unsigned)ohi << 32) | (unsigned)olo;
  return kmax(k, o);
}
template <int CTRL>
__device__ __forceinline__ unsigned long long dpp_kmin(unsigned long long k) {
  int lo = (int)(unsigned)(k & 0xFFFFFFFFull);
  int hi = (int)(unsigned)(k >> 32);
  int olo = __builtin_amdgcn_update_dpp(lo, lo, CTRL, 0xF, 0xF, false);
  int ohi = __builtin_amdgcn_update_dpp(hi, hi, CTRL, 0xF, 0xF, false);
  unsigned long long o = ((unsigned long long)(unsigned)ohi << 32) | (unsigned)olo;
  return kmin(k, o);
}
__device__ __forceinline__ unsigned long long swz16_kmax(unsigned long long k) {
  int lo = (int)(unsigned)(k & 0xFFFFFFFFull);
  int hi = (int)(unsigned)(k >> 32);
  int olo = __builtin_amdgcn_ds_swizzle(lo, 0x401F);
  int ohi = __builtin_amdgcn_ds_swizzle(hi, 0x401F);
  unsigned long long o = ((unsigned long long)(unsigned)ohi << 32) | (unsigned)olo;
  return kmax(k, o);
}
__device__ __forceinline__ unsigned long long swz16_kmin(unsigned long long k) {
  int lo = (int)(unsigned)(k & 0xFFFFFFFFull);
  int hi = (int)(unsigned)(k >> 32);
  int olo = __builtin_amdgcn_ds_swizzle(lo, 0x401F);
  int ohi = __builtin_amdgcn_ds_swizzle(hi, 0x401F);
  unsigned long long o = ((unsigned long long)(unsigned)ohi << 32) | (unsigned)olo;
  return kmin(k, o);
}

#define DPP_QUAD_XOR1 0xB1
#define DPP_QUAD_XOR2 0x4E
#define DPP_HALF_MIRR 0x141
#define DPP_ROW_MIRR  0x140

// ---------------------------------------------------------------------------
// FPS (round-3/8 exact, known-good 468us)
// ---------------------------------------------------------------------------
__global__ __launch_bounds__(512) void fps_kernel(const float* __restrict__ pts,
                                                  float* __restrict__ centers) {
#pragma clang fp contract(off)
  const int b = blockIdx.x;
  const float* pb = pts + (size_t)b * NP * 3;
  const int t = threadIdx.x;
  const int lane = t & 63, wid = t >> 6;     // 8 waves
  __shared__ float spx[NP], spy[NP], spz[NP];          // 96 KiB
  __shared__ unsigned long long swk[2][16];
  float px[16], py[16], pz[16], dd[16];
#pragma unroll
  for (int i = 0; i < 16; ++i) {
    int idx = t + i * 512;
    float x = pb[idx * 3 + 0], y = pb[idx * 3 + 1], z = pb[idx * 3 + 2];
    px[i] = x; py[i] = y; pz[i] = z; dd[i] = 1e10f;
    spx[idx] = x; spy[idx] = y; spz[idx] = z;
  }
  __syncthreads();
  float cx = spx[0], cy = spy[0], cz = spz[0];
  for (int g = 0; g < NG; ++g) {
    if (t == 0) {
      float* c = centers + ((size_t)b * NG + g) * 3;
      c[0] = cx; c[1] = cy; c[2] = cz;
    }
    float best = -1.0f; int bslot = 0;
#pragma unroll
    for (int i = 0; i < 16; ++i) {
      float dx = __fsub_rn(px[i], cx);
      float dy = __fsub_rn(py[i], cy);
      float dz = __fsub_rn(pz[i], cz);
      float d  = __fadd_rn(__fadd_rn(__fmul_rn(dx, dx), __fmul_rn(dy, dy)), __fmul_rn(dz, dz));
      dd[i] = fminf(dd[i], d);
      if (dd[i] > best) { best = dd[i]; bslot = i; }
    }
    int bidx = t + bslot * 512;
    unsigned long long key =
        ((unsigned long long)__float_as_uint(best) << 13) | (unsigned)(8191 - bidx);
    key = dpp_kmax<DPP_QUAD_XOR1>(key);
    key = dpp_kmax<DPP_QUAD_XOR2>(key);
    key = dpp_kmax<DPP_HALF_MIRR>(key);
    key = dpp_kmax<DPP_ROW_MIRR>(key);
    key = swz16_kmax(key);
    const int p = g & 1;
    if ((lane & 31) == 0) swk[p][wid * 2 + (lane >> 5)] = key;   // 16 entries
    __syncthreads();
    unsigned long long k2 = swk[p][lane & 15];
    k2 = dpp_kmax<DPP_QUAD_XOR1>(k2);
    k2 = dpp_kmax<DPP_QUAD_XOR2>(k2);
    k2 = dpp_kmax<DPP_HALF_MIRR>(k2);
    k2 = dpp_kmax<DPP_ROW_MIRR>(k2);
    int widx = 8191 - (int)(k2 & 0x1FFFull);
    cx = spx[widx]; cy = spy[widx]; cz = spz[widx];   // uniform broadcast read
  }
}

// ---------------------------------------------------------------------------
// kNN v3 (unchanged)
// ---------------------------------------------------------------------------
__global__ __launch_bounds__(256) void knn_kernel(const float* __restrict__ pts,
                                                  const float* __restrict__ centers,
                                                  int* __restrict__ knn_idx) {
#pragma clang fp contract(off)
  const int gg = blockIdx.x;
  const int b = gg >> 9;
  const float* pb = pts + (size_t)b * NP * 3;
  const float* c = centers + (size_t)gg * 3;
  const float cx = c[0], cy = c[1], cz = c[2];
  __shared__ unsigned long long swk[2][8];
  const int t = threadIdx.x, lane = t & 63, wid = t >> 6;
  float d[32];
  float lmin = 3e38f; int lidx = 0;
#pragma unroll
  for (int i = 0; i < 32; ++i) {
    int idx = i * 256 + t;
    float dx = __fsub_rn(cx, pb[idx * 3 + 0]);
    float dy = __fsub_rn(cy, pb[idx * 3 + 1]);
    float dz = __fsub_rn(cz, pb[idx * 3 + 2]);
    d[i] = __fadd_rn(__fadd_rn(__fmul_rn(dx, dx), __fmul_rn(dy, dy)), __fmul_rn(dz, dz));
    if (d[i] < lmin) { lmin = d[i]; lidx = idx; }
  }
  int* outp = knn_idx + (size_t)gg * NM;
  for (int r = 0; r < NM; ++r) {
    unsigned long long key =
        ((unsigned long long)__float_as_uint(lmin) << 13) | (unsigned)lidx;
    key = dpp_kmin<DPP_QUAD_XOR1>(key);
    key = dpp_kmin<DPP_QUAD_XOR2>(key);
    key = dpp_kmin<DPP_HALF_MIRR>(key);
    key = dpp_kmin<DPP_ROW_MIRR>(key);
    key = swz16_kmin(key);
    const int p = r & 1;
    if ((lane & 31) == 0) swk[p][wid * 2 + (lane >> 5)] = key;
    __syncthreads();
    unsigned long long k2 = swk[p][lane & 7];
    k2 = dpp_kmin<DPP_QUAD_XOR1>(k2);
    k2 = dpp_kmin<DPP_QUAD_XOR2>(k2);
    k2 = dpp_kmin<DPP_HALF_MIRR>(k2);
    int i0 = (int)(k2 & 0x1FFFull);
    if (t == 0) outp[r] = i0;
    if ((i0 & 255) == t) {
      int slot = i0 >> 8;
      lmin = 3e38f; lidx = 0;
#pragma unroll
      for (int i = 0; i < 32; ++i) {
        float di = (i == slot) ? 3e38f : d[i];
        d[i] = di;
        if (di < lmin) { lmin = di; lidx = i * 256 + t; }
      }
    }
  }
}

// ---------------------------------------------------------------------------
// quant (unchanged)
// ---------------------------------------------------------------------------
__global__ void quant_kernel(const float* __restrict__ W2, const float* __restrict__ W3,
                             const float* __restrict__ W4, const float* __restrict__ Wp2,
                             const float* __restrict__ b1, const float* __restrict__ g1,
                             const float* __restrict__ be1, const float* __restrict__ m1,
                             const float* __restrict__ v1, const float* __restrict__ g2,
                             const float* __restrict__ be2, const float* __restrict__ m2,
                             const float* __restrict__ v2,
                             f16* __restrict__ W2T, f16* __restrict__ W3aT,
                             f16* __restrict__ W3bT, f16* __restrict__ W4T,
                             f16* __restrict__ Wp2T,
                             float* __restrict__ s1, float* __restrict__ sh1,
                             float* __restrict__ s2, float* __restrict__ sh2) {
  int i = blockIdx.x * 256 + threadIdx.x;
  if (i < 32768) { int n = i >> 7, k = i & 127; W2T[i] = (f16)W2[(size_t)k * 256 + n]; return; }
  i -= 32768;
  if (i < 131072) { int n = i >> 8, k = i & 255; W3aT[i] = (f16)W3[(size_t)k * 512 + n]; return; }
  i -= 131072;
  if (i < 131072) { int n = i >> 8, k = i & 255; W3bT[i] = (f16)W3[(size_t)(256 + k) * 512 + n]; return; }
  i -= 131072;
  if (i < 196608) { int n = i >> 9, k = i & 511; W4T[i] = (f16)W4[(size_t)k * 384 + n]; return; }
  i -= 196608;
  if (i < 49152) { int n = i >> 7, k = i & 127; Wp2T[i] = (f16)Wp2[(size_t)k * 384 + n]; return; }
  i -= 49152;
  if (i < 128) {
    float s = g1[i] * rsqrtf(v1[i] + 1e-5f);
    s1[i] = s; sh1[i] = (b1[i] - m1[i]) * s + be1[i];
    return;
  }
  i -= 128;
  if (i < 512) {
    float s = g2[i] * rsqrtf(v2[i] + 1e-5f);
    s2[i] = s; sh2[i] = be2[i] - m2[i] * s;
    return;
  }
}

// ---------------------------------------------------------------------------
// l2f (unchanged): fused gather + L1 MLP + L2 GEMM + fg epilogue (+ f2 write)
// ---------------------------------------------------------------------------
template <int WRITE_F2>
__global__ __launch_bounds__(256) void l2f_kernel(const float* __restrict__ pts,
                                                  const float* __restrict__ centers,
                                                  const int* __restrict__ knn_idx,
                                                  const float* __restrict__ W1,
                                                  const float* __restrict__ s1,
                                                  const float* __restrict__ sh1,
                                                  const f16* __restrict__ W2T,
                                                  const float* __restrict__ b2,
                                                  f16* __restrict__ fg,
                                                  f16* __restrict__ f2, int grow0) {
  __shared__ __align__(16) f16 sF1[128 * 128];
  __shared__ float snb[128][3];
  const int t = threadIdx.x, lane = t & 63, wid = t >> 6;
  const int wr = wid >> 1, wc = wid & 1;
  const int l15 = lane & 15, lhi = lane >> 4;
  const int grow = grow0 + blockIdx.x * 128;
  const int y = blockIdx.y;

  if (t < 128) {
    int row = grow + t;
    int gg = row >> 5;
    int b = gg >> 9;
    int idx = knn_idx[(size_t)gg * NM + (row & 31)];
    const float* p = pts + ((size_t)b * NP + idx) * 3;
    const float* c = centers + (size_t)gg * 3;
    snb[t][0] = p[0] - c[0];
    snb[t][1] = p[1] - c[1];
    snb[t][2] = p[2] - c[2];
  }
  __syncthreads();
  {
    int row = t >> 1, c0 = (t & 1) * 64;
    float nx = snb[row][0], ny = snb[row][1], nz = snb[row][2];
    int sw = (row & 7) << 4;
#pragma unroll
    for (int cc = 0; cc < 64; cc += 8) {
      f16x8 v;
#pragma unroll
      for (int j = 0; j < 8; ++j) {
        int c = c0 + cc + j;
        float a = nx * W1[c] + ny * W1[128 + c] + nz * W1[256 + c];
        a = a * s1[c] + sh1[c];
        v[j] = (f16)fmaxf(a, 0.0f);
      }
      *(f16x8*)((char*)sF1 + row * 256 + (((c0 + cc) * 2) ^ sw)) = v;
    }
  }
  __syncthreads();

  f32x4 acc[4][4];
#pragma unroll
  for (int m = 0; m < 4; ++m)
#pragma unroll
    for (int n = 0; n < 4; ++n) acc[m][n] = (f32x4){0.f, 0.f, 0.f, 0.f};

  const f16* Wb = W2T + (size_t)(y * 128) * 128;
#pragma unroll
  for (int ks = 0; ks < 4; ++ks) {
    f16x8 af[4], bf[4];
#pragma unroll
    for (int m = 0; m < 4; ++m) {
      int row = wr * 64 + m * 16 + l15;
      af[m] = *(const f16x8*)((const char*)sF1 + row * 256 + ((ks * 64 + lhi * 16) ^ ((row & 7) << 4)));
    }
#pragma unroll
    for (int n = 0; n < 4; ++n) {
      int nr = wc * 64 + n * 16 + l15;
      bf[n] = *(const f16x8*)(Wb + (size_t)nr * 128 + ks * 32 + lhi * 8);
    }
#pragma unroll
    for (int m = 0; m < 4; ++m)
#pragma unroll
      for (int n = 0; n < 4; ++n)
        acc[m][n] = __builtin_amdgcn_mfma_f32_16x16x32_f16(af[m], bf[n], acc[m][n], 0, 0, 0);
  }

  float bias[4];
#pragma unroll
  for (int n = 0; n < 4; ++n) bias[n] = b2[y * 128 + wc * 64 + n * 16 + l15];
#pragma unroll
  for (int p = 0; p < 2; ++p) {
#pragma unroll
    for (int n = 0; n < 4; ++n) {
      float v = acc[2 * p][n][0];
#pragma unroll
      for (int i = 1; i < 4; ++i) v = fmaxf(v, acc[2 * p][n][i]);
#pragma unroll
      for (int i = 0; i < 4; ++i) v = fmaxf(v, acc[2 * p + 1][n][i]);
      v = fmaxf(v, __shfl_xor(v, 16));
      v = fmaxf(v, __shfl_xor(v, 32));
      if (lhi == 0)
        fg[(size_t)((grow >> 5) + wr * 2 + p) * 256 + y * 128 + wc * 64 + n * 16 + l15] =
            (f16)(v + bias[n]);
    }
  }

  if (WRITE_F2) {
    __syncthreads();
    f16* sF2 = sF1;
#pragma unroll
    for (int n = 0; n < 4; ++n) {
      int col = wc * 64 + n * 16 + l15;
#pragma unroll
      for (int m = 0; m < 4; ++m)
#pragma unroll
        for (int i = 0; i < 4; ++i) {
          int row = wr * 64 + m * 16 + lhi * 4 + i;
          sF2[row * 128 + col] = (f16)(acc[m][n][i] + bias[n]);
        }
    }
    __syncthreads();
#pragma unroll
    for (int ch = 0; ch < 8; ++ch) {
      int off = ch * 4096 + t * 16;
      int row = off >> 8, cb = off & 255;
      *(uint4*)((char*)f2 + (size_t)(blockIdx.x * 128 + row) * 512 + y * 256 + cb) =
          *(const uint4*)((const char*)sF2 + off);
    }
  }
}

// ---------------------------------------------------------------------------
// gemm128 v2: 128x128 tile, BK=64, 4 waves, DOUBLE-BUFFERED global_load_lds
// prefetch with counted vmcnt (T3/T4 2-phase: never drain-0 in main loop).
// EPI 1: L3  (+g3 global, *s2 +sh2, relu) -> f16
// EPI 2: L4  group-max +b4 -> out_x f32
// EPI 3: f32 out + bias (g3 gemm)
// EPI 4: pos out (strided [B,513,384]) + bias
// ---------------------------------------------------------------------------
template <int K, int EPI>
__global__ __launch_bounds__(256) void gemm128_kernel(const f16* __restrict__ A,
                                                      const f16* __restrict__ BT,
                                                      float* __restrict__ outF32,
                                                      f16* __restrict__ outF16,
                                                      const float* __restrict__ e0,
                                                      const float* __restrict__ e1,
                                                      const float* __restrict__ e2,
                                                      int NTOT, int gg0) {
  __shared__ __align__(16) f16 sA[2][128 * 64];   // 16 KiB x2
  __shared__ __align__(16) f16 sB[2][128 * 64];   // 16 KiB x2
  const int t = threadIdx.x, lane = t & 63, wid = t >> 6;
  const int wrow = wid >> 1, wcol = wid & 1;
  const int l15 = lane & 15, lhi = lane >> 4;
  f32x4 acc[4][4];
#pragma unroll
  for (int m = 0; m < 4; ++m)
#pragma unroll
    for (int n = 0; n < 4; ++n) acc[m][n] = (f32x4){0.f, 0.f, 0.f, 0.f};

  const size_t arow0 = (size_t)blockIdx.x * 128;
  const int ncol0 = blockIdx.y * 128;
  const char* Ab = (const char*)A;
  const char* Bb = (const char*)BT;
  const int so = wid * 1024 + lane * 16;
  const int cb = so & 127;
  const int r0 = so >> 7;
  const int KSTEPS = K / 64;

  // stage k-tile kt into buffer bsel (8 global_load_lds per thread)
  auto STAGE = [&](int bsel, int kt) {
#pragma unroll
    for (int rnd = 0; rnd < 4; ++rnd) {
      int r = rnd * 32 + r0;
      int sw = (r & 7) << 4;
      gl_lds16(Ab + (arow0 + r) * (size_t)(K * 2) + kt * 128 + (cb ^ sw),
               (char*)sA[bsel] + rnd * 4096 + wid * 1024);
      gl_lds16(Bb + (size_t)(ncol0 + r) * (K * 2) + kt * 128 + (cb ^ sw),
               (char*)sB[bsel] + rnd * 4096 + wid * 1024);
    }
  };

  STAGE(0, 0);
  int cur = 0;
#pragma unroll
  for (int kt = 0; kt < KSTEPS; ++kt) {
    if (kt + 1 < KSTEPS) {
      STAGE(cur ^ 1, kt + 1);
      asm volatile("s_waitcnt vmcnt(8)" ::: "memory");   // current tile's 8 done
    } else {
      asm volatile("s_waitcnt vmcnt(0)" ::: "memory");
    }
    __builtin_amdgcn_s_barrier();
#pragma unroll
    for (int ks = 0; ks < 2; ++ks) {
      f16x8 af[4], bf[4];
#pragma unroll
      for (int m = 0; m < 4; ++m) {
        int row = wrow * 64 + m * 16 + l15;
        int addr = row * 128 + ((ks * 64 + lhi * 16) ^ ((row & 7) << 4));
        af[m] = *(const f16x8*)((const char*)sA[cur] + addr);
      }
#pragma unroll
      for (int n = 0; n < 4; ++n) {
        int nrow = wcol * 64 + n * 16 + l15;
        int addr = nrow * 128 + ((ks * 64 + lhi * 16) ^ ((nrow & 7) << 4));
        bf[n] = *(const f16x8*)((const char*)sB[cur] + addr);
      }
#pragma unroll
      for (int m = 0; m < 4; ++m)
#pragma unroll
        for (int n = 0; n < 4; ++n)
          acc[m][n] = __builtin_amdgcn_mfma_f32_16x16x32_f16(af[m], bf[n], acc[m][n], 0, 0, 0);
    }
    asm volatile("" ::: "memory");
    __builtin_amdgcn_s_barrier();
    cur ^= 1;
  }

  if (EPI == 1) {
#pragma unroll
    for (int n = 0; n < 4; ++n) {
      int col = ncol0 + wcol * 64 + n * 16 + l15;
      float s = e1[col], sh = e2[col];
#pragma unroll
      for (int m = 0; m < 4; ++m) {
        int grp = gg0 + blockIdx.x * 4 + wrow * 2 + (m >> 1);
        float gv = e0[(size_t)grp * 512 + col];
#pragma unroll
        for (int i = 0; i < 4; ++i) {
          size_t row = arow0 + wrow * 64 + m * 16 + lhi * 4 + i;
          float v = (acc[m][n][i] + gv) * s + sh;
          outF16[row * NTOT + col] = (f16)fmaxf(v, 0.0f);
        }
      }
    }
  } else if (EPI == 2) {
#pragma unroll
    for (int pr = 0; pr < 2; ++pr) {
      size_t gg_glob = (size_t)gg0 + blockIdx.x * 4 + wrow * 2 + pr;
#pragma unroll
      for (int n = 0; n < 4; ++n) {
        float v = acc[2 * pr][n][0];
#pragma unroll
        for (int i = 1; i < 4; ++i) v = fmaxf(v, acc[2 * pr][n][i]);
#pragma unroll
        for (int i = 0; i < 4; ++i) v = fmaxf(v, acc[2 * pr + 1][n][i]);
        v = fmaxf(v, __shfl_xor(v, 16));
        v = fmaxf(v, __shfl_xor(v, 32));
        if (lhi == 0) {
          int col = ncol0 + wcol * 64 + n * 16 + l15;
          outF32[gg_glob * ENC + col] = v + e0[col];
        }
      }
    }
  } else if (EPI == 3) {
#pragma unroll
    for (int n = 0; n < 4; ++n) {
      int col = ncol0 + wcol * 64 + n * 16 + l15;
      float bias = e0[col];
#pragma unroll
      for (int m = 0; m < 4; ++m)
#pragma unroll
        for (int i = 0; i < 4; ++i) {
          size_t row = arow0 + wrow * 64 + m * 16 + lhi * 4 + i;
          outF32[row * NTOT + col] = acc[m][n][i] + bias;
        }
    }
  } else {  // EPI 4: pos out (strided [B,513,384])
#pragma unroll
    for (int n = 0; n < 4; ++n) {
      int col = ncol0 + wcol * 64 + n * 16 + l15;
      float bias = e0[col];
#pragma unroll
      for (int m = 0; m < 4; ++m)
#pragma unroll
        for (int i = 0; i < 4; ++i) {
          size_t row = arow0 + wrow * 64 + m * 16 + lhi * 4 + i;
          int b = (int)(row >> 9), g = (int)(row & 511);
          outF32[((size_t)b * 513 + 1 + g) * 384 + col] = acc[m][n][i] + bias;
        }
    }
  }
}

// ---------------------------------------------------------------------------
__global__ __launch_bounds__(256) void posh_kernel(const float* __restrict__ centers,
                                                   const float* __restrict__ Wp1,
                                                   const float* __restrict__ bp1,
                                                   f16* __restrict__ h) {
  int o = blockIdx.x * 256 + threadIdx.x;
  int row = o >> 7, c = o & 127;
  const float* ct = centers + (size_t)row * 3;
  float x = ct[0] * Wp1[c] + ct[1] * Wp1[128 + c] + ct[2] * Wp1[256 + c] + bp1[c];
  float u = 0.7978845608028654f * (x + 0.044715f * x * x * x);
  h[o] = (f16)(0.5f * x * (1.0f + tanhf(u)));
}

__global__ void cls_kernel(const float* __restrict__ cls_pos, float* __restrict__ out_pos) {
  out_pos[(size_t)blockIdx.x * (NG + 1) * ENC + threadIdx.x] = cls_pos[threadIdx.x];
}

// ---------------------------------------------------------------------------
extern "C" void kernel_launch(void* const* d_in, const int* in_sizes, int n_in,
                              void* d_out, int out_size, void* d_ws, size_t ws_size,
                              hipStream_t stream) {
  const float* pts = (const float*)d_in[0];
  const float* W1  = (const float*)d_in[1];
  const float* b1  = (const float*)d_in[2];
  const float* g1  = (const float*)d_in[3];
  const float* be1 = (const float*)d_in[4];
  const float* m1  = (const float*)d_in[5];
  const float* v1  = (const float*)d_in[6];
  const float* W2  = (const float*)d_in[7];
  const float* b2  = (const float*)d_in[8];
  const float* W3  = (const float*)d_in[9];
  const float* b3  = (const float*)d_in[10];
  const float* g2  = (const float*)d_in[11];
  const float* be2 = (const float*)d_in[12];
  const float* m2  = (const float*)d_in[13];
  const float* v2  = (const float*)d_in[14];
  const float* W4  = (const float*)d_in[15];
  const float* b4  = (const float*)d_in[16];
  const float* Wp1 = (const float*)d_in[17];
  const float* bp1 = (const float*)d_in[18];
  const float* Wp2 = (const float*)d_in[19];
  const float* bp2 = (const float*)d_in[20];
  const float* cls = (const float*)d_in[21];

  float* out_x   = (float*)d_out;
  float* out_pos = out_x + (size_t)NB * NG * ENC;

  char* w = (char*)d_ws;
  auto alloc = [&](size_t bytes) {
    char* p = w;
    w += (bytes + 255) & ~(size_t)255;
    return p;
  };
  float* centers = (float*)alloc((size_t)NB * NG * 3 * 4);
  int*   knn     = (int*)alloc((size_t)NB * NG * NM * 4);
  f16*   W2T     = (f16*)alloc(32768 * 2);
  f16*   W3aT    = (f16*)alloc(131072 * 2);
  f16*   W3bT    = (f16*)alloc(131072 * 2);
  f16*   W4T     = (f16*)alloc(196608 * 2);
  f16*   Wp2T    = (f16*)alloc(49152 * 2);
  float* s1      = (float*)alloc(128 * 4);
  float* sh1     = (float*)alloc(128 * 4);
  float* s2      = (float*)alloc(512 * 4);
  float* sh2     = (float*)alloc(512 * 4);
  f16*   fg      = (f16*)alloc((size_t)8192 * 256 * 2);
  float* g3      = (float*)alloc((size_t)8192 * 512 * 4);
  f16*   h       = (f16*)alloc((size_t)8192 * 128 * 2);
  size_t fixed = (size_t)(w - (char*)d_ws);
  const size_t f2_full = (size_t)NROWS * 256 * 2;   // 128 MiB
  const size_t f3_full = (size_t)NROWS * 512 * 2;   // 256 MiB

  quant_kernel<<<dim3(2115), dim3(256), 0, stream>>>(W2, W3, W4, Wp2, b1, g1, be1, m1, v1,
                                                     g2, be2, m2, v2, W2T, W3aT, W3bT, W4T,
                                                     Wp2T, s1, sh1, s2, sh2);
  fps_kernel<<<dim3(NB), dim3(512), 0, stream>>>(pts, centers);
  knn_kernel<<<dim3(NB * NG), dim3(256), 0, stream>>>(pts, centers, knn);

  if (ws_size >= fixed + f2_full + f3_full / 2 + 4096) {
    // 2 chunks: f2 full; f3 in 2 LLC-resident chunks (128 MiB each)
    f16* f2  = (f16*)alloc(f2_full);
    f16* f3c = (f16*)alloc(f3_full / 2);
    l2f_kernel<1><<<dim3(2048, 2), dim3(256), 0, stream>>>(pts, centers, knn, W1, s1, sh1,
                                                           W2T, b2, fg, f2, 0);
    gemm128_kernel<256, 3><<<dim3(64, 4), dim3(256), 0, stream>>>(
        fg, W3aT, g3, nullptr, b3, nullptr, nullptr, 512, 0);
    for (int c = 0; c < 2; ++c) {
      gemm128_kernel<256, 1><<<dim3(1024, 4), dim3(256), 0, stream>>>(
          f2 + (size_t)c * 131072 * 256, W3bT, nullptr, f3c, g3, s2, sh2, 512, c * 4096);
      gemm128_kernel<512, 2><<<dim3(1024, 3), dim3(256), 0, stream>>>(
          f3c, W4T, out_x, nullptr, b4, nullptr, nullptr, 384, c * 4096);
    }
  } else if (ws_size >= fixed + f2_full + f3_full / 4 + 4096) {
    // 4 chunks (proven fallback)
    f16* f2  = (f16*)alloc(f2_full);
    f16* f3c = (f16*)alloc(f3_full / 4);
    l2f_kernel<1><<<dim3(2048, 2), dim3(256), 0, stream>>>(pts, centers, knn, W1, s1, sh1,
                                                           W2T, b2, fg, f2, 0);
    gemm128_kernel<256, 3><<<dim3(64, 4), dim3(256), 0, stream>>>(
        fg, W3aT, g3, nullptr, b3, nullptr, nullptr, 512, 0);
    for (int c = 0; c < 4; ++c) {
      gemm128_kernel<256, 1><<<dim3(512, 4), dim3(256), 0, stream>>>(
          f2 + (size_t)c * 65536 * 256, W3bT, nullptr, f3c, g3, s2, sh2, 512, c * 2048);
      gemm128_kernel<512, 2><<<dim3(512, 3), dim3(256), 0, stream>>>(
          f3c, W4T, out_x, nullptr, b4, nullptr, nullptr, 384, c * 2048);
    }
  } else {
    // LOW: fg prepass + 8 chunks of {l2f-write, L3, L4}
    f16* f2c = (f16*)alloc((size_t)32768 * 256 * 2);
    f16* f3c = (f16*)alloc((size_t)32768 * 512 * 2);
    l2f_kernel<0><<<dim3(2048, 2), dim3(256), 0, stream>>>(pts, centers, knn, W1, s1, sh1,
                                                           W2T, b2, fg, nullptr, 0);
    gemm128_kernel<256, 3><<<dim3(64, 4), dim3(256), 0, stream>>>(
        fg, W3aT, g3, nullptr, b3, nullptr, nullptr, 512, 0);
    for (int c = 0; c < 8; ++c) {
      l2f_kernel<1><<<dim3(256, 2), dim3(256), 0, stream>>>(pts, centers, knn, W1, s1, sh1,
                                                            W2T, b2, fg, f2c, c * 32768);
      gemm128_kernel<256, 1><<<dim3(256, 4), dim3(256), 0, stream>>>(
          f2c, W3bT, nullptr, f3c, g3, s2, sh2, 512, c * 1024);
      gemm128_kernel<512, 2><<<dim3(256, 3), dim3(256), 0, stream>>>(
          f3c, W4T, out_x, nullptr, b4, nullptr, nullptr, 384, c * 1024);
    }
  }

  posh_kernel<<<dim3(4096), dim3(256), 0, stream>>>(centers, Wp1, bp1, h);
  gemm128_kernel<128, 4><<<dim3(64, 3), dim3(256), 0, stream>>>(
      h, Wp2T, out_pos, nullptr, bp2, nullptr, nullptr, 384, 0);
  cls_kernel<<<dim3(NB), dim3(ENC), 0, stream>>>(cls, out_pos);
}